// Round 16
// baseline (72.128 us; speedup 1.0000x reference)
//
#include <hip/hip_runtime.h>

typedef __attribute__((ext_vector_type(8))) short bf16x8;
typedef __attribute__((ext_vector_type(4))) float f32x4;
typedef __attribute__((ext_vector_type(8))) unsigned short u16x8;

constexpr int Bn = 16;
constexpr int Nn = 512;
constexpr int Fn = 64;
constexpr int Aout = 512;

static __device__ __forceinline__ unsigned short f2bf(float f) {
  union { float f; unsigned int u; } v; v.f = f;
  unsigned int r = v.u + 0x7fffu + ((v.u >> 16) & 1u);
  return (unsigned short)(r >> 16);
}
static __device__ __forceinline__ float bf2f(unsigned short u) {
  union { unsigned int u; float f; } v; v.u = ((unsigned int)u) << 16;
  return v.f;
}
static __device__ __forceinline__ unsigned int pk2(float a, float b) {
  union { float f; unsigned int u; } ua, ub; ua.f = a; ub.f = b;
  return ((ua.u + 0x8000u) >> 16) | ((ub.u + 0x8000u) & 0xFFFF0000u);
}
static __device__ __forceinline__ void gload_lds16(const float* g, float* l) {
  __builtin_amdgcn_global_load_lds(
      (const __attribute__((address_space(1))) void*)g,
      (__attribute__((address_space(3))) void*)l, 16, 0, 0);
}

// B-perm (X/B-operand fragment layout), cols c, contraction k, K total:
//   frag = (c>>4)*(K/32) + (k>>5); off = frag*512 + ((c&15) + 16*((k>>3)&3))*8 + (k&7)

// ---------------------------------------------------------------------------
// prep (weights only)
// ---------------------------------------------------------------------------
__launch_bounds__(256)
__global__ void prep_kernel(const float* __restrict__ Wi,
                            unsigned short* __restrict__ Wp,
                            const float* __restrict__ W0,
                            const float* __restrict__ W1,
                            const float* __restrict__ W2,
                            const float* __restrict__ W3,
                            unsigned short* __restrict__ Wall) {
  const int blk = blockIdx.x;
  if (blk < 16) {
    const int idx = blk * 256 + threadIdx.x;  // [0,4096)
    const int f = idx >> 6, o = idx & 63;
    const int k0 = o * 8;
    const size_t dst = ((size_t)((f >> 4) * 16 + (k0 >> 5)) << 9) +
                       (((f & 15) + 16 * ((k0 >> 3) & 3)) << 3);
    unsigned short w[8];
#pragma unroll
    for (int j = 0; j < 8; ++j) w[j] = f2bf(Wi[(size_t)(k0 + j) * Fn + f]);
    *(uint4*)(Wp + dst) = *(const uint4*)w;
  } else {
    const int r = blk - 16;
    const int mat = r >> 1;  // 0..11 = l*4 + m (m: W3,W0,W1,W2)
    const int l = mat >> 2, m = mat & 3;
    const int idx = (r & 1) * 256 + threadIdx.x;  // [0,512)
    const int co = idx >> 3, oct = idx & 7;
    const int k0 = oct * 8;
    const float* src = (m == 0 ? W3 : m == 1 ? W0 : m == 2 ? W1 : W2) + l * 4096;
    const size_t dst = (size_t)mat * 4096 +
                       ((size_t)((co >> 4) * 2 + (k0 >> 5)) << 9) +
                       (((co & 15) + 16 * ((k0 >> 3) & 3)) << 3);
    unsigned short w[8];
#pragma unroll
    for (int j = 0; j < 8; ++j) w[j] = f2bf(src[(k0 + j) * 64 + co]);
    *(uint4*)(Wall + dst) = *(const uint4*)w;
  }
}

// ---------------------------------------------------------------------------
// h0 kernel (v16: 16-row tiles, grid 512, 2 blocks/CU):
// h0 = relu(BN_init(hs @ Wi)). Wave w owns f-cols [w*16, w*16+16).
// ---------------------------------------------------------------------------
__launch_bounds__(256, 2)
__global__ void h0_kernel(const float* __restrict__ hs,
                          const unsigned short* __restrict__ Wp,
                          const float* __restrict__ mean,
                          const float* __restrict__ var,
                          const float* __restrict__ gamma,
                          const float* __restrict__ beta,
                          unsigned short* __restrict__ operm,
                          unsigned short* __restrict__ olin) {
  const int b = blockIdx.y;
  const int R0 = blockIdx.x * 16;
  const int tid = threadIdx.x;
  const int w = tid >> 6, l = tid & 63;
  const int lr = l & 15, q = l >> 4;

  const float* Af = hs + ((size_t)b << 18) + (size_t)(R0 + lr) * 512 + q * 8;
  const unsigned short* Xf = Wp + (size_t)w * 8192 + l * 8;

  f32x4 acc = {0.f, 0.f, 0.f, 0.f};
  float4 ral[2][2];
  bf16x8 xb[2];
#define LD0(S_, T_)                                                       \
  {                                                                       \
    ral[S_][0] = *(const float4*)(Af + (T_)*32);                          \
    ral[S_][1] = *(const float4*)(Af + (T_)*32 + 4);                      \
    xb[S_] = *(const bf16x8*)(Xf + (T_)*512);                             \
  }
  LD0(0, 0)
#pragma unroll
  for (int t = 0; t < 16; ++t) {
    const int cur = t & 1;
    if (t + 1 < 16) LD0(cur ^ 1, t + 1)
    union { bf16x8 v; unsigned int u[4]; } cv;
    cv.u[0] = pk2(ral[cur][0].x, ral[cur][0].y);
    cv.u[1] = pk2(ral[cur][0].z, ral[cur][0].w);
    cv.u[2] = pk2(ral[cur][1].x, ral[cur][1].y);
    cv.u[3] = pk2(ral[cur][1].z, ral[cur][1].w);
    acc = __builtin_amdgcn_mfma_f32_16x16x32_bf16(cv.v, xb[cur], acc, 0, 0, 0);
  }
#undef LD0

  __shared__ __align__(16) unsigned short Tfn[64][24];  // [f][n 16+pad]
  __shared__ __align__(16) unsigned short Tnf[16][72];  // [n][f]
  float sc[4], mu[4], bt[4];
#pragma unroll
  for (int i = 0; i < 4; ++i) {
    int n = R0 + q * 4 + i;
    sc[i] = rsqrtf(var[n] + 1e-5f) * gamma[n];
    mu[i] = mean[n];
    bt[i] = beta[n];
  }
  {
    const int f = w * 16 + lr;
    ushort4 wv;
#pragma unroll
    for (int i = 0; i < 4; ++i) {
      float v = fmaxf(fmaf(acc[i] - mu[i], sc[i], bt[i]), 0.f);
      unsigned short uv = f2bf(v);
      ((unsigned short*)&wv)[i] = uv;
      Tnf[q * 4 + i][f] = uv;
    }
    *(ushort4*)&Tfn[f][q * 4] = wv;
  }
  __syncthreads();
  if (tid < 128) {
    const int f = tid >> 1, o = tid & 1;
    const int n = R0 + o * 8;
    const size_t dst = ((size_t)b << 15) +
                       ((size_t)((f >> 4) * 16 + (n >> 5)) << 9) +
                       (((f & 15) + 16 * ((n >> 3) & 3)) << 3);
    *(uint4*)(operm + dst) = *(const uint4*)&Tfn[f][o * 8];
    const int nl = tid >> 3, oc8 = tid & 7;
    *(uint4*)(olin + ((size_t)b << 15) + (size_t)(R0 + nl) * 64 + oc8 * 8) =
        *(const uint4*)&Tnf[nl][oc8 * 8];
  }
}

// ---------------------------------------------------------------------------
// layer kernel (r12-proven): 16-row tiles, grid 512 (2 blocks/CU), BK=64.
// phase A: fp32 adjacency staged LDS-direct (XOR-preswizzled source);
// X (B-perm) depth-2 VGPR prefetch. phase B fused.
// ---------------------------------------------------------------------------
struct LArgs {
  const float* Af0;
  const float* Af1;
  const float* Af2;
  const unsigned short* Xh;
  const unsigned short* XP[3];
  const unsigned short* hlin;
  const unsigned short* Wl;
  const float *bias, *mean, *var, *gamma, *beta;
  unsigned short* hperm_o;
  unsigned short* hlin_o;
  unsigned short* Po[3];
};

template <int NSEG>
__launch_bounds__(256, 2)
__global__ void layer_kernel(LArgs La) {
  const int flat = blockIdx.x;  // 512; flat&7 = XCD
  const int b = (flat & 7) + 8 * ((flat >> 3) & 1);
  const int R0 = (flat >> 4) * 16;
  const int tid = threadIdx.x;
  const int w = tid >> 6, l = tid & 63;
  const int lr = l & 15, q = l >> 4;

  __shared__ __align__(16) float Asg[2][3][16][64];        // 24 KB
  __shared__ __align__(16) unsigned short Tnf[3][16][72];  // [z][n][f]
  __shared__ __align__(16) unsigned short Tfn[3][64][24];  // [z][f][n]
  __shared__ __align__(16) unsigned short Hfn[64][24];
  __shared__ __align__(16) unsigned short Hnf[16][72];

  const float* Az = (w == 0) ? La.Af0 : (w == 1) ? La.Af1 : La.Af2;
  const float* Abase = Az + ((size_t)b << 18) + (size_t)R0 * 512;
  size_t aoff[4];
#pragma unroll
  for (int c = 0; c < 4; ++c) {
    const int arow = c * 4 + (l >> 4);
    const int agc = (l & 15) ^ arow;
    aoff[c] = (size_t)arow * 512 + agc * 4;
  }

  const size_t xoff = ((size_t)b << 15) + (size_t)w * 8192 + l * 8;
  const unsigned short* Xhp = La.Xh + xoff;
  const unsigned short* XP0p = (NSEG == 2) ? La.XP[0] + xoff : Xhp;
  const unsigned short* XP1p = (NSEG == 2) ? La.XP[1] + xoff : Xhp;
  const unsigned short* XP2p = (NSEG == 2) ? La.XP[2] + xoff : Xhp;

  f32x4 acc[3] = {{0.f, 0.f, 0.f, 0.f},
                  {0.f, 0.f, 0.f, 0.f},
                  {0.f, 0.f, 0.f, 0.f}};
  bf16x8 rxh[2][2];
  bf16x8 rxp[2][3][2];

#define STAGE(BB, T)                                                     \
  if (w < 3) {                                                           \
    _Pragma("unroll") for (int c = 0; c < 4; ++c)                        \
        gload_lds16(Abase + aoff[c] + (T)*64, &Asg[BB][w][c * 4][0]);    \
  }
#define LOADX(S_, T_)                                                    \
  {                                                                      \
    rxh[S_][0] = *(const bf16x8*)(Xhp + (2 * (T_)) * 512);               \
    rxh[S_][1] = *(const bf16x8*)(Xhp + (2 * (T_) + 1) * 512);           \
    if (NSEG == 2) {                                                     \
      rxp[S_][0][0] = *(const bf16x8*)(XP0p + (2 * (T_)) * 512);         \
      rxp[S_][0][1] = *(const bf16x8*)(XP0p + (2 * (T_) + 1) * 512);     \
      rxp[S_][1][0] = *(const bf16x8*)(XP1p + (2 * (T_)) * 512);         \
      rxp[S_][1][1] = *(const bf16x8*)(XP1p + (2 * (T_) + 1) * 512);     \
      rxp[S_][2][0] = *(const bf16x8*)(XP2p + (2 * (T_)) * 512);         \
      rxp[S_][2][1] = *(const bf16x8*)(XP2p + (2 * (T_) + 1) * 512);     \
    }                                                                    \
  }

  STAGE(0, 0)
  LOADX(0, 0)
  __syncthreads();

#pragma unroll
  for (int t = 0; t < 8; ++t) {
    const int cur = t & 1;
    if (t + 1 < 8) {
      STAGE(cur ^ 1, t + 1)
      LOADX(cur ^ 1, t + 1)
    }
#pragma unroll
    for (int kf = 0; kf < 2; ++kf) {
      float4 fa[3], fb[3];
#pragma unroll
      for (int z = 0; z < 3; ++z) {
        fa[z] = *(const float4*)&Asg[cur][z][lr][((kf * 8 + 2 * q) ^ lr) << 2];
        fb[z] = *(const float4*)&Asg[cur][z][lr][((kf * 8 + 2 * q + 1) ^ lr) << 2];
      }
      bf16x8 azf[3];
#pragma unroll
      for (int z = 0; z < 3; ++z) {
        union { bf16x8 v; unsigned int u[4]; } cv;
        cv.u[0] = pk2(fa[z].x, fa[z].y);
        cv.u[1] = pk2(fa[z].z, fa[z].w);
        cv.u[2] = pk2(fb[z].x, fb[z].y);
        cv.u[3] = pk2(fb[z].z, fb[z].w);
        azf[z] = cv.v;
      }
      bf16x8 asumf;
      if (NSEG == 2) {
        union { bf16x8 v; unsigned int u[4]; } cv;
        cv.u[0] = pk2(fa[0].x + fa[1].x + fa[2].x, fa[0].y + fa[1].y + fa[2].y);
        cv.u[1] = pk2(fa[0].z + fa[1].z + fa[2].z, fa[0].w + fa[1].w + fa[2].w);
        cv.u[2] = pk2(fb[0].x + fb[1].x + fb[2].x, fb[0].y + fb[1].y + fb[2].y);
        cv.u[3] = pk2(fb[0].z + fb[1].z + fb[2].z, fb[0].w + fb[1].w + fb[2].w);
        asumf = cv.v;
      }
#pragma unroll
      for (int z = 0; z < 3; ++z) {
        acc[z] = __builtin_amdgcn_mfma_f32_16x16x32_bf16(azf[z], rxh[cur][kf],
                                                         acc[z], 0, 0, 0);
        if (NSEG == 2)
          acc[z] = __builtin_amdgcn_mfma_f32_16x16x32_bf16(
              asumf, rxp[cur][z][kf], acc[z], 0, 0, 0);
      }
    }
    __syncthreads();
  }
#undef STAGE
#undef LOADX

#pragma unroll
  for (int z = 0; z < 3; ++z) {
    const int f = w * 16 + lr;
    ushort4 wv;
#pragma unroll
    for (int i = 0; i < 4; ++i) {
      unsigned short uv = f2bf(acc[z][i]);
      ((unsigned short*)&wv)[i] = uv;
      Tnf[z][q * 4 + i][f] = uv;
    }
    *(ushort4*)&Tfn[z][f][q * 4] = wv;
  }
  __syncthreads();

  if (La.Po[0] != nullptr && tid < 128) {
    const int f = tid >> 1, o = tid & 1;
    const int n = R0 + o * 8;
    const size_t dst = ((size_t)b << 15) +
                       ((size_t)((f >> 4) * 16 + (n >> 5)) << 9) +
                       (((f & 15) + 16 * ((n >> 3) & 3)) << 3);
#pragma unroll
    for (int z = 0; z < 3; ++z)
      *(uint4*)(La.Po[z] + dst) = *(const uint4*)&Tfn[z][f][o * 8];
  }

  f32x4 acch = {0.f, 0.f, 0.f, 0.f};
#pragma unroll
  for (int m = 0; m < 4; ++m) {
#pragma unroll
    for (int ks = 0; ks < 2; ++ks) {
      bf16x8 af;
      if (m == 0)
        af = *(const bf16x8*)(La.hlin + ((size_t)b << 15) +
                              (size_t)(R0 + lr) * 64 + q * 8 + ks * 32);
      else
        af = *(const bf16x8*)&Tnf[m - 1][lr][q * 8 + ks * 32];
      const bf16x8 bf_ = *(const bf16x8*)(La.Wl + m * 4096 +
                                          ((size_t)(w * 2 + ks) << 9) + l * 8);
      acch = __builtin_amdgcn_mfma_f32_16x16x32_bf16(af, bf_, acch, 0, 0, 0);
    }
  }

  {
    float sc[4], mu[4], bt[4];
#pragma unroll
    for (int i = 0; i < 4; ++i) {
      int n = R0 + q * 4 + i;
      sc[i] = rsqrtf(La.var[n] + 1e-5f) * La.gamma[n];
      mu[i] = La.mean[n];
      bt[i] = La.beta[n];
    }
    const int f = w * 16 + lr;
    const float bia = La.bias[f];
    ushort4 wv;
#pragma unroll
    for (int i = 0; i < 4; ++i) {
      float v = acch[i] + bia;
      v = fmaxf(fmaf(v - mu[i], sc[i], bt[i]), 0.f);
      unsigned short uv = f2bf(v);
      ((unsigned short*)&wv)[i] = uv;
      Hnf[q * 4 + i][f] = uv;
    }
    *(ushort4*)&Hfn[f][q * 4] = wv;
  }
  __syncthreads();

  if (tid < 128) {
    const int f = tid >> 1, o = tid & 1;
    const int n = R0 + o * 8;
    const size_t dst = ((size_t)b << 15) +
                       ((size_t)((f >> 4) * 16 + (n >> 5)) << 9) +
                       (((f & 15) + 16 * ((n >> 3) & 3)) << 3);
    *(uint4*)(La.hperm_o + dst) = *(const uint4*)&Hfn[f][o * 8];
    if (La.hlin_o != nullptr) {
      const int nl = tid >> 3, oc8 = tid & 7;
      *(uint4*)(La.hlin_o + ((size_t)b << 15) + (size_t)(R0 + nl) * 64 +
                oc8 * 8) = *(const uint4*)&Hnf[nl][oc8 * 8];
    }
  }
}

// ---------------------------------------------------------------------------
// head: sum over n (B-perm h3) -> BN+ReLU -> FC(512) -> softmax. block per b.
// ---------------------------------------------------------------------------
__launch_bounds__(256)
__global__ void head_kernel(const unsigned short* __restrict__ h3p,
                            const float* __restrict__ gmean,
                            const float* __restrict__ gvar,
                            const float* __restrict__ ggamma,
                            const float* __restrict__ gbeta,
                            const float* __restrict__ fc_w,
                            const float* __restrict__ fc_b,
                            float* __restrict__ out) {
  const int b = blockIdx.x;
  const int t = threadIdx.x;
  __shared__ float part[256];
  __shared__ float gh[64];
  __shared__ float red[256];

  const int f = t >> 2, q = t & 3;
  const unsigned short* hp = h3p + ((size_t)b << 15);
  float s = 0.f;
#pragma unroll
  for (int m = 0; m < 16; ++m) {
    const int n = q * 128 + m * 8;
    const size_t off = ((size_t)((f >> 4) * 16 + (n >> 5)) << 9) +
                       (((f & 15) + 16 * ((n >> 3) & 3)) << 3);
    u16x8 v = *(const u16x8*)(hp + off);
#pragma unroll
    for (int e = 0; e < 8; ++e) s += bf2f((unsigned short)v[e]);
  }
  part[t] = s;
  __syncthreads();
  if (t < 64) {
    float sum = part[t * 4] + part[t * 4 + 1] + part[t * 4 + 2] + part[t * 4 + 3];
    float sc = rsqrtf(gvar[t] + 1e-5f) * ggamma[t];
    float v = fmaf(sum - gmean[t], sc, gbeta[t]);
    gh[t] = v > 0.f ? v : 0.f;
  }
  __syncthreads();

  float lg[2];
#pragma unroll
  for (int rep = 0; rep < 2; ++rep) {
    const int a = t + rep * 256;
    const float* __restrict__ wv = fc_w + (size_t)a * Fn;
    float acc = fc_b[a];
#pragma unroll 8
    for (int kk = 0; kk < 64; ++kk) acc = fmaf(gh[kk], wv[kk], acc);
    lg[rep] = acc;
  }
  red[t] = fmaxf(lg[0], lg[1]);
  __syncthreads();
  for (int off = 128; off > 0; off >>= 1) {
    if (t < off) red[t] = fmaxf(red[t], red[t + off]);
    __syncthreads();
  }
  const float mx = red[0];
  __syncthreads();
  const float e0 = __expf(lg[0] - mx), e1 = __expf(lg[1] - mx);
  red[t] = e0 + e1;
  __syncthreads();
  for (int off = 128; off > 0; off >>= 1) {
    if (t < off) red[t] += red[t + off];
    __syncthreads();
  }
  const float inv = 1.f / red[0];
  out[(size_t)b * Aout + t] = e0 * inv;
  out[(size_t)b * Aout + t + 256] = e1 * inv;
}

// ---------------------------------------------------------------------------
extern "C" void kernel_launch(void* const* d_in, const int* in_sizes, int n_in,
                              void* d_out, int out_size, void* d_ws,
                              size_t ws_size, hipStream_t stream) {
  (void)in_sizes; (void)n_in; (void)out_size; (void)ws_size;
  const float* hs_init = (const float*)d_in[0];
  const float* adjs0 = (const float*)d_in[1];
  const float* adjs1 = (const float*)d_in[2];
  const float* adjs2 = (const float*)d_in[3];
  const float* W_init = (const float*)d_in[4];
  const float* W0 = (const float*)d_in[5];
  const float* W1 = (const float*)d_in[6];
  const float* W2 = (const float*)d_in[7];
  const float* W3 = (const float*)d_in[8];
  const float* bvec = (const float*)d_in[9];
  const float* fc1_w = (const float*)d_in[10];
  const float* fc1_b = (const float*)d_in[11];
  const float* bn_init_mean = (const float*)d_in[12];
  const float* bn_init_var = (const float*)d_in[13];
  const float* bn_init_gamma = (const float*)d_in[14];
  const float* bn_init_beta = (const float*)d_in[15];
  const float* bn_layer_mean = (const float*)d_in[16];
  const float* bn_layer_var = (const float*)d_in[17];
  const float* bn_layer_gamma = (const float*)d_in[18];
  const float* bn_layer_beta = (const float*)d_in[19];
  const float* bn_graph_mean = (const float*)d_in[20];
  const float* bn_graph_var = (const float*)d_in[21];
  const float* bn_graph_gamma = (const float*)d_in[22];
  const float* bn_graph_beta = (const float*)d_in[23];

  const size_t NF = (size_t)Bn * Fn * Nn;  // 524,288

  unsigned short* wsu = (unsigned short*)d_ws;
  unsigned short* Wp = wsu;            // 32768
  unsigned short* Wall = Wp + 32768;   // 49152
  unsigned short* hApe = Wall + 49152;
  unsigned short* hBpe = hApe + NF;
  unsigned short* hAli = hBpe + NF;
  unsigned short* hBli = hAli + NF;
  unsigned short* PA0 = hBli + NF;
  unsigned short* PA1 = PA0 + NF;
  unsigned short* PA2 = PA1 + NF;
  unsigned short* PB0 = PA2 + NF;
  unsigned short* PB1 = PB0 + NF;
  unsigned short* PB2 = PB1 + NF;

  prep_kernel<<<dim3(40), dim3(256), 0, stream>>>(W_init, Wp, W0, W1, W2, W3,
                                                  Wall);

  h0_kernel<<<dim3(32, Bn), dim3(256), 0, stream>>>(
      hs_init, Wp, bn_init_mean, bn_init_var, bn_init_gamma, bn_init_beta,
      hApe, hAli);

  // L0
  {
    LArgs La = {};
    La.Af0 = adjs0; La.Af1 = adjs1; La.Af2 = adjs2;
    La.Xh = hApe; La.hlin = hAli;
    La.Wl = Wall;
    La.bias = bvec; La.mean = bn_layer_mean; La.var = bn_layer_var;
    La.gamma = bn_layer_gamma; La.beta = bn_layer_beta;
    La.hperm_o = hBpe; La.hlin_o = hBli;
    La.Po[0] = PA0; La.Po[1] = PA1; La.Po[2] = PA2;
    layer_kernel<1><<<dim3(512), dim3(256), 0, stream>>>(La);
  }
  // L1
  {
    LArgs La = {};
    La.Af0 = adjs0; La.Af1 = adjs1; La.Af2 = adjs2;
    La.Xh = hBpe; La.hlin = hBli;
    La.XP[0] = PA0; La.XP[1] = PA1; La.XP[2] = PA2;
    La.Wl = Wall + 4 * 4096;
    La.bias = bvec + 64; La.mean = bn_layer_mean + 512;
    La.var = bn_layer_var + 512; La.gamma = bn_layer_gamma + 512;
    La.beta = bn_layer_beta + 512;
    La.hperm_o = hApe; La.hlin_o = hAli;
    La.Po[0] = PB0; La.Po[1] = PB1; La.Po[2] = PB2;
    layer_kernel<2><<<dim3(512), dim3(256), 0, stream>>>(La);
  }
  // L2
  {
    LArgs La = {};
    La.Af0 = adjs0; La.Af1 = adjs1; La.Af2 = adjs2;
    La.Xh = hApe; La.hlin = hAli;
    La.XP[0] = PB0; La.XP[1] = PB1; La.XP[2] = PB2;
    La.Wl = Wall + 8 * 4096;
    La.bias = bvec + 128; La.mean = bn_layer_mean + 1024;
    La.var = bn_layer_var + 1024; La.gamma = bn_layer_gamma + 1024;
    La.beta = bn_layer_beta + 1024;
    La.hperm_o = hBpe; La.hlin_o = nullptr;
    La.Po[0] = nullptr; La.Po[1] = nullptr; La.Po[2] = nullptr;
    layer_kernel<2><<<dim3(512), dim3(256), 0, stream>>>(La);
  }

  head_kernel<<<dim3(Bn), dim3(256), 0, stream>>>(
      hBpe, bn_graph_mean, bn_graph_var, bn_graph_gamma, bn_graph_beta, fc1_w,
      fc1_b, (float*)d_out);
}

// Round 17
// 68.827 us; speedup vs baseline: 1.0480x; 1.0480x over previous
//
#include <hip/hip_runtime.h>

typedef __attribute__((ext_vector_type(8))) short bf16x8;
typedef __attribute__((ext_vector_type(4))) float f32x4;
typedef __attribute__((ext_vector_type(8))) unsigned short u16x8;

constexpr int Bn = 16;
constexpr int Nn = 512;
constexpr int Fn = 64;
constexpr int Aout = 512;

static __device__ __forceinline__ unsigned short f2bf(float f) {
  union { float f; unsigned int u; } v; v.f = f;
  unsigned int r = v.u + 0x7fffu + ((v.u >> 16) & 1u);
  return (unsigned short)(r >> 16);
}
static __device__ __forceinline__ float bf2f(unsigned short u) {
  union { unsigned int u; float f; } v; v.u = ((unsigned int)u) << 16;
  return v.f;
}
static __device__ __forceinline__ unsigned int pk2(float a, float b) {
  union { float f; unsigned int u; } ua, ub; ua.f = a; ub.f = b;
  return ((ua.u + 0x8000u) >> 16) | ((ub.u + 0x8000u) & 0xFFFF0000u);
}
static __device__ __forceinline__ void gload_lds16(const float* g, float* l) {
  __builtin_amdgcn_global_load_lds(
      (const __attribute__((address_space(1))) void*)g,
      (__attribute__((address_space(3))) void*)l, 16, 0, 0);
}

// B-perm (X/B-operand fragment layout), cols c, contraction k, K total:
//   frag = (c>>4)*(K/32) + (k>>5); off = frag*512 + ((c&15) + 16*((k>>3)&3))*8 + (k&7)

// ---------------------------------------------------------------------------
// prep (weights only)
// ---------------------------------------------------------------------------
__launch_bounds__(256)
__global__ void prep_kernel(const float* __restrict__ Wi,
                            unsigned short* __restrict__ Wp,
                            const float* __restrict__ W0,
                            const float* __restrict__ W1,
                            const float* __restrict__ W2,
                            const float* __restrict__ W3,
                            unsigned short* __restrict__ Wall) {
  const int blk = blockIdx.x;
  if (blk < 16) {
    const int idx = blk * 256 + threadIdx.x;  // [0,4096)
    const int f = idx >> 6, o = idx & 63;
    const int k0 = o * 8;
    const size_t dst = ((size_t)((f >> 4) * 16 + (k0 >> 5)) << 9) +
                       (((f & 15) + 16 * ((k0 >> 3) & 3)) << 3);
    unsigned short w[8];
#pragma unroll
    for (int j = 0; j < 8; ++j) w[j] = f2bf(Wi[(size_t)(k0 + j) * Fn + f]);
    *(uint4*)(Wp + dst) = *(const uint4*)w;
  } else {
    const int r = blk - 16;
    const int mat = r >> 1;  // 0..11 = l*4 + m (m: W3,W0,W1,W2)
    const int l = mat >> 2, m = mat & 3;
    const int idx = (r & 1) * 256 + threadIdx.x;  // [0,512)
    const int co = idx >> 3, oct = idx & 7;
    const int k0 = oct * 8;
    const float* src = (m == 0 ? W3 : m == 1 ? W0 : m == 2 ? W1 : W2) + l * 4096;
    const size_t dst = (size_t)mat * 4096 +
                       ((size_t)((co >> 4) * 2 + (k0 >> 5)) << 9) +
                       (((co & 15) + 16 * ((k0 >> 3) & 3)) << 3);
    unsigned short w[8];
#pragma unroll
    for (int j = 0; j < 8; ++j) w[j] = f2bf(src[(k0 + j) * 64 + co]);
    *(uint4*)(Wall + dst) = *(const uint4*)w;
  }
}

// ---------------------------------------------------------------------------
// h0 kernel (32-row tiles, grid 256): h0 = relu(BN_init(hs @ Wi)).
// wave w: rows (w&1)*16, f-cols (w>>1)*32. Depth-2 reg prefetch.
// ---------------------------------------------------------------------------
__launch_bounds__(256, 1)
__global__ void h0_kernel(const float* __restrict__ hs,
                          const unsigned short* __restrict__ Wp,
                          const float* __restrict__ mean,
                          const float* __restrict__ var,
                          const float* __restrict__ gamma,
                          const float* __restrict__ beta,
                          unsigned short* __restrict__ operm,
                          unsigned short* __restrict__ olin) {
  const int b = blockIdx.y;
  const int R0 = blockIdx.x * 32;
  const int tid = threadIdx.x;
  const int w = tid >> 6, l = tid & 63;
  const int lr = l & 15, q = l >> 4;
  const int nsub = (w & 1) * 16;
  const int cstart = (w >> 1) * 2;

  const float* Af =
      hs + ((size_t)b << 18) + (size_t)(R0 + nsub + lr) * 512 + q * 8;
  const unsigned short* Xf = Wp + cstart * 8192 + l * 8;

  f32x4 acc[2] = {{0.f, 0.f, 0.f, 0.f}, {0.f, 0.f, 0.f, 0.f}};
  float4 ral[2][2];
  bf16x8 xb[2][2];
#define LD0(S_, T_)                                                       \
  {                                                                       \
    ral[S_][0] = *(const float4*)(Af + (T_)*32);                          \
    ral[S_][1] = *(const float4*)(Af + (T_)*32 + 4);                      \
    xb[S_][0] = *(const bf16x8*)(Xf + (T_)*512);                          \
    xb[S_][1] = *(const bf16x8*)(Xf + 8192 + (T_)*512);                   \
  }
  LD0(0, 0)
#pragma unroll
  for (int t = 0; t < 16; ++t) {
    const int cur = t & 1;
    if (t + 1 < 16) LD0(cur ^ 1, t + 1)
    union { bf16x8 v; unsigned int u[4]; } cv;
    cv.u[0] = pk2(ral[cur][0].x, ral[cur][0].y);
    cv.u[1] = pk2(ral[cur][0].z, ral[cur][0].w);
    cv.u[2] = pk2(ral[cur][1].x, ral[cur][1].y);
    cv.u[3] = pk2(ral[cur][1].z, ral[cur][1].w);
#pragma unroll
    for (int c = 0; c < 2; ++c)
      acc[c] = __builtin_amdgcn_mfma_f32_16x16x32_bf16(cv.v, xb[cur][c], acc[c], 0, 0, 0);
  }
#undef LD0

  __shared__ __align__(16) unsigned short Tfn[64][40];
  __shared__ __align__(16) unsigned short Tnf[32][72];
  float sc[4], mu[4], bt[4];
#pragma unroll
  for (int i = 0; i < 4; ++i) {
    int n = R0 + nsub + q * 4 + i;
    sc[i] = rsqrtf(var[n] + 1e-5f) * gamma[n];
    mu[i] = mean[n];
    bt[i] = beta[n];
  }
#pragma unroll
  for (int c = 0; c < 2; ++c) {
    const int f = (cstart + c) * 16 + lr;
    ushort4 wv;
#pragma unroll
    for (int i = 0; i < 4; ++i) {
      float v = fmaxf(fmaf(acc[c][i] - mu[i], sc[i], bt[i]), 0.f);
      unsigned short uv = f2bf(v);
      ((unsigned short*)&wv)[i] = uv;
      Tnf[nsub + q * 4 + i][f] = uv;
    }
    *(ushort4*)&Tfn[f][nsub + q * 4] = wv;
  }
  __syncthreads();
  {
    const int f = tid >> 2, oc = tid & 3;
    const int n = R0 + oc * 8;
    const size_t dst = ((size_t)b << 15) +
                       ((size_t)((f >> 4) * 16 + (n >> 5)) << 9) +
                       (((f & 15) + 16 * ((n >> 3) & 3)) << 3);
    *(uint4*)(operm + dst) = *(const uint4*)&Tfn[f][oc * 8];
    const int nl = tid >> 3, oc8 = tid & 7;
    *(uint4*)(olin + ((size_t)b << 15) + (size_t)(R0 + nl) * 64 + oc8 * 8) =
        *(const uint4*)&Tnf[nl][oc8 * 8];
  }
}

// ---------------------------------------------------------------------------
// layer kernel (r12-proven): 16-row tiles, grid 512 (2 blocks/CU), BK=64.
// phase A: fp32 adjacency staged LDS-direct (XOR-preswizzled source);
// X (B-perm) depth-2 VGPR prefetch. phase B fused.
// ---------------------------------------------------------------------------
struct LArgs {
  const float* Af0;
  const float* Af1;
  const float* Af2;
  const unsigned short* Xh;
  const unsigned short* XP[3];
  const unsigned short* hlin;
  const unsigned short* Wl;
  const float *bias, *mean, *var, *gamma, *beta;
  unsigned short* hperm_o;
  unsigned short* hlin_o;
  unsigned short* Po[3];
};

template <int NSEG>
__launch_bounds__(256, 2)
__global__ void layer_kernel(LArgs La) {
  const int flat = blockIdx.x;  // 512; flat&7 = XCD
  const int b = (flat & 7) + 8 * ((flat >> 3) & 1);
  const int R0 = (flat >> 4) * 16;
  const int tid = threadIdx.x;
  const int w = tid >> 6, l = tid & 63;
  const int lr = l & 15, q = l >> 4;

  __shared__ __align__(16) float Asg[2][3][16][64];        // 24 KB
  __shared__ __align__(16) unsigned short Tnf[3][16][72];  // [z][n][f]
  __shared__ __align__(16) unsigned short Tfn[3][64][24];  // [z][f][n]
  __shared__ __align__(16) unsigned short Hfn[64][24];
  __shared__ __align__(16) unsigned short Hnf[16][72];

  const float* Az = (w == 0) ? La.Af0 : (w == 1) ? La.Af1 : La.Af2;
  const float* Abase = Az + ((size_t)b << 18) + (size_t)R0 * 512;
  size_t aoff[4];
#pragma unroll
  for (int c = 0; c < 4; ++c) {
    const int arow = c * 4 + (l >> 4);
    const int agc = (l & 15) ^ arow;
    aoff[c] = (size_t)arow * 512 + agc * 4;
  }

  const size_t xoff = ((size_t)b << 15) + (size_t)w * 8192 + l * 8;
  const unsigned short* Xhp = La.Xh + xoff;
  const unsigned short* XP0p = (NSEG == 2) ? La.XP[0] + xoff : Xhp;
  const unsigned short* XP1p = (NSEG == 2) ? La.XP[1] + xoff : Xhp;
  const unsigned short* XP2p = (NSEG == 2) ? La.XP[2] + xoff : Xhp;

  f32x4 acc[3] = {{0.f, 0.f, 0.f, 0.f},
                  {0.f, 0.f, 0.f, 0.f},
                  {0.f, 0.f, 0.f, 0.f}};
  bf16x8 rxh[2][2];
  bf16x8 rxp[2][3][2];

#define STAGE(BB, T)                                                     \
  if (w < 3) {                                                           \
    _Pragma("unroll") for (int c = 0; c < 4; ++c)                        \
        gload_lds16(Abase + aoff[c] + (T)*64, &Asg[BB][w][c * 4][0]);    \
  }
#define LOADX(S_, T_)                                                    \
  {                                                                      \
    rxh[S_][0] = *(const bf16x8*)(Xhp + (2 * (T_)) * 512);               \
    rxh[S_][1] = *(const bf16x8*)(Xhp + (2 * (T_) + 1) * 512);           \
    if (NSEG == 2) {                                                     \
      rxp[S_][0][0] = *(const bf16x8*)(XP0p + (2 * (T_)) * 512);         \
      rxp[S_][0][1] = *(const bf16x8*)(XP0p + (2 * (T_) + 1) * 512);     \
      rxp[S_][1][0] = *(const bf16x8*)(XP1p + (2 * (T_)) * 512);         \
      rxp[S_][1][1] = *(const bf16x8*)(XP1p + (2 * (T_) + 1) * 512);     \
      rxp[S_][2][0] = *(const bf16x8*)(XP2p + (2 * (T_)) * 512);         \
      rxp[S_][2][1] = *(const bf16x8*)(XP2p + (2 * (T_) + 1) * 512);     \
    }                                                                    \
  }

  STAGE(0, 0)
  LOADX(0, 0)
  __syncthreads();

#pragma unroll
  for (int t = 0; t < 8; ++t) {
    const int cur = t & 1;
    if (t + 1 < 8) {
      STAGE(cur ^ 1, t + 1)
      LOADX(cur ^ 1, t + 1)
    }
#pragma unroll
    for (int kf = 0; kf < 2; ++kf) {
      float4 fa[3], fb[3];
#pragma unroll
      for (int z = 0; z < 3; ++z) {
        fa[z] = *(const float4*)&Asg[cur][z][lr][((kf * 8 + 2 * q) ^ lr) << 2];
        fb[z] = *(const float4*)&Asg[cur][z][lr][((kf * 8 + 2 * q + 1) ^ lr) << 2];
      }
      bf16x8 azf[3];
#pragma unroll
      for (int z = 0; z < 3; ++z) {
        union { bf16x8 v; unsigned int u[4]; } cv;
        cv.u[0] = pk2(fa[z].x, fa[z].y);
        cv.u[1] = pk2(fa[z].z, fa[z].w);
        cv.u[2] = pk2(fb[z].x, fb[z].y);
        cv.u[3] = pk2(fb[z].z, fb[z].w);
        azf[z] = cv.v;
      }
      bf16x8 asumf;
      if (NSEG == 2) {
        union { bf16x8 v; unsigned int u[4]; } cv;
        cv.u[0] = pk2(fa[0].x + fa[1].x + fa[2].x, fa[0].y + fa[1].y + fa[2].y);
        cv.u[1] = pk2(fa[0].z + fa[1].z + fa[2].z, fa[0].w + fa[1].w + fa[2].w);
        cv.u[2] = pk2(fb[0].x + fb[1].x + fb[2].x, fb[0].y + fb[1].y + fb[2].y);
        cv.u[3] = pk2(fb[0].z + fb[1].z + fb[2].z, fb[0].w + fb[1].w + fb[2].w);
        asumf = cv.v;
      }
#pragma unroll
      for (int z = 0; z < 3; ++z) {
        acc[z] = __builtin_amdgcn_mfma_f32_16x16x32_bf16(azf[z], rxh[cur][kf],
                                                         acc[z], 0, 0, 0);
        if (NSEG == 2)
          acc[z] = __builtin_amdgcn_mfma_f32_16x16x32_bf16(
              asumf, rxp[cur][z][kf], acc[z], 0, 0, 0);
      }
    }
    __syncthreads();
  }
#undef STAGE
#undef LOADX

#pragma unroll
  for (int z = 0; z < 3; ++z) {
    const int f = w * 16 + lr;
    ushort4 wv;
#pragma unroll
    for (int i = 0; i < 4; ++i) {
      unsigned short uv = f2bf(acc[z][i]);
      ((unsigned short*)&wv)[i] = uv;
      Tnf[z][q * 4 + i][f] = uv;
    }
    *(ushort4*)&Tfn[z][f][q * 4] = wv;
  }
  __syncthreads();

  if (La.Po[0] != nullptr && tid < 128) {
    const int f = tid >> 1, o = tid & 1;
    const int n = R0 + o * 8;
    const size_t dst = ((size_t)b << 15) +
                       ((size_t)((f >> 4) * 16 + (n >> 5)) << 9) +
                       (((f & 15) + 16 * ((n >> 3) & 3)) << 3);
#pragma unroll
    for (int z = 0; z < 3; ++z)
      *(uint4*)(La.Po[z] + dst) = *(const uint4*)&Tfn[z][f][o * 8];
  }

  f32x4 acch = {0.f, 0.f, 0.f, 0.f};
#pragma unroll
  for (int m = 0; m < 4; ++m) {
#pragma unroll
    for (int ks = 0; ks < 2; ++ks) {
      bf16x8 af;
      if (m == 0)
        af = *(const bf16x8*)(La.hlin + ((size_t)b << 15) +
                              (size_t)(R0 + lr) * 64 + q * 8 + ks * 32);
      else
        af = *(const bf16x8*)&Tnf[m - 1][lr][q * 8 + ks * 32];
      const bf16x8 bf_ = *(const bf16x8*)(La.Wl + m * 4096 +
                                          ((size_t)(w * 2 + ks) << 9) + l * 8);
      acch = __builtin_amdgcn_mfma_f32_16x16x32_bf16(af, bf_, acch, 0, 0, 0);
    }
  }

  {
    float sc[4], mu[4], bt[4];
#pragma unroll
    for (int i = 0; i < 4; ++i) {
      int n = R0 + q * 4 + i;
      sc[i] = rsqrtf(La.var[n] + 1e-5f) * La.gamma[n];
      mu[i] = La.mean[n];
      bt[i] = La.beta[n];
    }
    const int f = w * 16 + lr;
    const float bia = La.bias[f];
    ushort4 wv;
#pragma unroll
    for (int i = 0; i < 4; ++i) {
      float v = acch[i] + bia;
      v = fmaxf(fmaf(v - mu[i], sc[i], bt[i]), 0.f);
      unsigned short uv = f2bf(v);
      ((unsigned short*)&wv)[i] = uv;
      Hnf[q * 4 + i][f] = uv;
    }
    *(ushort4*)&Hfn[f][q * 4] = wv;
  }
  __syncthreads();

  if (tid < 128) {
    const int f = tid >> 1, o = tid & 1;
    const int n = R0 + o * 8;
    const size_t dst = ((size_t)b << 15) +
                       ((size_t)((f >> 4) * 16 + (n >> 5)) << 9) +
                       (((f & 15) + 16 * ((n >> 3) & 3)) << 3);
    *(uint4*)(La.hperm_o + dst) = *(const uint4*)&Hfn[f][o * 8];
    if (La.hlin_o != nullptr) {
      const int nl = tid >> 3, oc8 = tid & 7;
      *(uint4*)(La.hlin_o + ((size_t)b << 15) + (size_t)(R0 + nl) * 64 +
                oc8 * 8) = *(const uint4*)&Hnf[nl][oc8 * 8];
    }
  }
}

// ---------------------------------------------------------------------------
// head: sum over n (B-perm h3) -> BN+ReLU -> FC(512) -> softmax. block per b.
// ---------------------------------------------------------------------------
__launch_bounds__(256)
__global__ void head_kernel(const unsigned short* __restrict__ h3p,
                            const float* __restrict__ gmean,
                            const float* __restrict__ gvar,
                            const float* __restrict__ ggamma,
                            const float* __restrict__ gbeta,
                            const float* __restrict__ fc_w,
                            const float* __restrict__ fc_b,
                            float* __restrict__ out) {
  const int b = blockIdx.x;
  const int t = threadIdx.x;
  __shared__ float part[256];
  __shared__ float gh[64];
  __shared__ float red[256];

  const int f = t >> 2, q = t & 3;
  const unsigned short* hp = h3p + ((size_t)b << 15);
  float s = 0.f;
#pragma unroll
  for (int m = 0; m < 16; ++m) {
    const int n = q * 128 + m * 8;
    const size_t off = ((size_t)((f >> 4) * 16 + (n >> 5)) << 9) +
                       (((f & 15) + 16 * ((n >> 3) & 3)) << 3);
    u16x8 v = *(const u16x8*)(hp + off);
#pragma unroll
    for (int e = 0; e < 8; ++e) s += bf2f((unsigned short)v[e]);
  }
  part[t] = s;
  __syncthreads();
  if (t < 64) {
    float sum = part[t * 4] + part[t * 4 + 1] + part[t * 4 + 2] + part[t * 4 + 3];
    float sc = rsqrtf(gvar[t] + 1e-5f) * ggamma[t];
    float v = fmaf(sum - gmean[t], sc, gbeta[t]);
    gh[t] = v > 0.f ? v : 0.f;
  }
  __syncthreads();

  float lg[2];
#pragma unroll
  for (int rep = 0; rep < 2; ++rep) {
    const int a = t + rep * 256;
    const float* __restrict__ wv = fc_w + (size_t)a * Fn;
    float acc = fc_b[a];
#pragma unroll 8
    for (int kk = 0; kk < 64; ++kk) acc = fmaf(gh[kk], wv[kk], acc);
    lg[rep] = acc;
  }
  red[t] = fmaxf(lg[0], lg[1]);
  __syncthreads();
  for (int off = 128; off > 0; off >>= 1) {
    if (t < off) red[t] = fmaxf(red[t], red[t + off]);
    __syncthreads();
  }
  const float mx = red[0];
  __syncthreads();
  const float e0 = __expf(lg[0] - mx), e1 = __expf(lg[1] - mx);
  red[t] = e0 + e1;
  __syncthreads();
  for (int off = 128; off > 0; off >>= 1) {
    if (t < off) red[t] += red[t + off];
    __syncthreads();
  }
  const float inv = 1.f / red[0];
  out[(size_t)b * Aout + t] = e0 * inv;
  out[(size_t)b * Aout + t + 256] = e1 * inv;
}

// ---------------------------------------------------------------------------
extern "C" void kernel_launch(void* const* d_in, const int* in_sizes, int n_in,
                              void* d_out, int out_size, void* d_ws,
                              size_t ws_size, hipStream_t stream) {
  (void)in_sizes; (void)n_in; (void)out_size; (void)ws_size;
  const float* hs_init = (const float*)d_in[0];
  const float* adjs0 = (const float*)d_in[1];
  const float* adjs1 = (const float*)d_in[2];
  const float* adjs2 = (const float*)d_in[3];
  const float* W_init = (const float*)d_in[4];
  const float* W0 = (const float*)d_in[5];
  const float* W1 = (const float*)d_in[6];
  const float* W2 = (const float*)d_in[7];
  const float* W3 = (const float*)d_in[8];
  const float* bvec = (const float*)d_in[9];
  const float* fc1_w = (const float*)d_in[10];
  const float* fc1_b = (const float*)d_in[11];
  const float* bn_init_mean = (const float*)d_in[12];
  const float* bn_init_var = (const float*)d_in[13];
  const float* bn_init_gamma = (const float*)d_in[14];
  const float* bn_init_beta = (const float*)d_in[15];
  const float* bn_layer_mean = (const float*)d_in[16];
  const float* bn_layer_var = (const float*)d_in[17];
  const float* bn_layer_gamma = (const float*)d_in[18];
  const float* bn_layer_beta = (const float*)d_in[19];
  const float* bn_graph_mean = (const float*)d_in[20];
  const float* bn_graph_var = (const float*)d_in[21];
  const float* bn_graph_gamma = (const float*)d_in[22];
  const float* bn_graph_beta = (const float*)d_in[23];

  const size_t NF = (size_t)Bn * Fn * Nn;  // 524,288

  unsigned short* wsu = (unsigned short*)d_ws;
  unsigned short* Wp = wsu;            // 32768
  unsigned short* Wall = Wp + 32768;   // 49152
  unsigned short* hApe = Wall + 49152;
  unsigned short* hBpe = hApe + NF;
  unsigned short* hAli = hBpe + NF;
  unsigned short* hBli = hAli + NF;
  unsigned short* PA0 = hBli + NF;
  unsigned short* PA1 = PA0 + NF;
  unsigned short* PA2 = PA1 + NF;
  unsigned short* PB0 = PA2 + NF;
  unsigned short* PB1 = PB0 + NF;
  unsigned short* PB2 = PB1 + NF;

  prep_kernel<<<dim3(40), dim3(256), 0, stream>>>(W_init, Wp, W0, W1, W2, W3,
                                                  Wall);

  h0_kernel<<<dim3(16, Bn), dim3(256), 0, stream>>>(
      hs_init, Wp, bn_init_mean, bn_init_var, bn_init_gamma, bn_init_beta,
      hApe, hAli);

  // L0
  {
    LArgs La = {};
    La.Af0 = adjs0; La.Af1 = adjs1; La.Af2 = adjs2;
    La.Xh = hApe; La.hlin = hAli;
    La.Wl = Wall;
    La.bias = bvec; La.mean = bn_layer_mean; La.var = bn_layer_var;
    La.gamma = bn_layer_gamma; La.beta = bn_layer_beta;
    La.hperm_o = hBpe; La.hlin_o = hBli;
    La.Po[0] = PA0; La.Po[1] = PA1; La.Po[2] = PA2;
    layer_kernel<1><<<dim3(512), dim3(256), 0, stream>>>(La);
  }
  // L1
  {
    LArgs La = {};
    La.Af0 = adjs0; La.Af1 = adjs1; La.Af2 = adjs2;
    La.Xh = hBpe; La.hlin = hBli;
    La.XP[0] = PA0; La.XP[1] = PA1; La.XP[2] = PA2;
    La.Wl = Wall + 4 * 4096;
    La.bias = bvec + 64; La.mean = bn_layer_mean + 512;
    La.var = bn_layer_var + 512; La.gamma = bn_layer_gamma + 512;
    La.beta = bn_layer_beta + 512;
    La.hperm_o = hApe; La.hlin_o = hAli;
    La.Po[0] = PB0; La.Po[1] = PB1; La.Po[2] = PB2;
    layer_kernel<2><<<dim3(512), dim3(256), 0, stream>>>(La);
  }
  // L2
  {
    LArgs La = {};
    La.Af0 = adjs0; La.Af1 = adjs1; La.Af2 = adjs2;
    La.Xh = hApe; La.hlin = hAli;
    La.XP[0] = PB0; La.XP[1] = PB1; La.XP[2] = PB2;
    La.Wl = Wall + 8 * 4096;
    La.bias = bvec + 128; La.mean = bn_layer_mean + 1024;
    La.var = bn_layer_var + 1024; La.gamma = bn_layer_gamma + 1024;
    La.beta = bn_layer_beta + 1024;
    La.hperm_o = hBpe; La.hlin_o = nullptr;
    La.Po[0] = nullptr; La.Po[1] = nullptr; La.Po[2] = nullptr;
    layer_kernel<2><<<dim3(512), dim3(256), 0, stream>>>(La);
  }

  head_kernel<<<dim3(Bn), dim3(256), 0, stream>>>(
      hBpe, bn_graph_mean, bn_graph_var, bn_graph_gamma, bn_graph_beta, fc1_w,
      fc1_b, (float*)d_out);
}

// Round 18
// 65.806 us; speedup vs baseline: 1.0961x; 1.0459x over previous
//
#include <hip/hip_runtime.h>

typedef __attribute__((ext_vector_type(8))) short bf16x8;
typedef __attribute__((ext_vector_type(4))) float f32x4;
typedef __attribute__((ext_vector_type(8))) unsigned short u16x8;

constexpr int Bn = 16;
constexpr int Nn = 512;
constexpr int Fn = 64;
constexpr int Aout = 512;

static __device__ __forceinline__ unsigned short f2bf(float f) {
  union { float f; unsigned int u; } v; v.f = f;
  unsigned int r = v.u + 0x7fffu + ((v.u >> 16) & 1u);
  return (unsigned short)(r >> 16);
}
static __device__ __forceinline__ float bf2f(unsigned short u) {
  union { unsigned int u; float f; } v; v.u = ((unsigned int)u) << 16;
  return v.f;
}
static __device__ __forceinline__ unsigned int pk2(float a, float b) {
  union { float f; unsigned int u; } ua, ub; ua.f = a; ub.f = b;
  return ((ua.u + 0x8000u) >> 16) | ((ub.u + 0x8000u) & 0xFFFF0000u);
}
static __device__ __forceinline__ void gload_lds16(const float* g, float* l) {
  __builtin_amdgcn_global_load_lds(
      (const __attribute__((address_space(1))) void*)g,
      (__attribute__((address_space(3))) void*)l, 16, 0, 0);
}
static __device__ __forceinline__ void gload_lds16b(const unsigned short* g,
                                                    unsigned short* l) {
  __builtin_amdgcn_global_load_lds(
      (const __attribute__((address_space(1))) void*)g,
      (__attribute__((address_space(3))) void*)l, 16, 0, 0);
}

// B-perm (X/B-operand fragment layout), cols c, contraction k, K total:
//   frag = (c>>4)*(K/32) + (k>>5); off = frag*512 + ((c&15) + 16*((k>>3)&3))*8 + (k&7)

// ---------------------------------------------------------------------------
// prep (weights only)
// ---------------------------------------------------------------------------
__launch_bounds__(256)
__global__ void prep_kernel(const float* __restrict__ Wi,
                            unsigned short* __restrict__ Wp,
                            const float* __restrict__ W0,
                            const float* __restrict__ W1,
                            const float* __restrict__ W2,
                            const float* __restrict__ W3,
                            unsigned short* __restrict__ Wall) {
  const int blk = blockIdx.x;
  if (blk < 16) {
    const int idx = blk * 256 + threadIdx.x;  // [0,4096)
    const int f = idx >> 6, o = idx & 63;
    const int k0 = o * 8;
    const size_t dst = ((size_t)((f >> 4) * 16 + (k0 >> 5)) << 9) +
                       (((f & 15) + 16 * ((k0 >> 3) & 3)) << 3);
    unsigned short w[8];
#pragma unroll
    for (int j = 0; j < 8; ++j) w[j] = f2bf(Wi[(size_t)(k0 + j) * Fn + f]);
    *(uint4*)(Wp + dst) = *(const uint4*)w;
  } else {
    const int r = blk - 16;
    const int mat = r >> 1;  // 0..11 = l*4 + m (m: W3,W0,W1,W2)
    const int l = mat >> 2, m = mat & 3;
    const int idx = (r & 1) * 256 + threadIdx.x;  // [0,512)
    const int co = idx >> 3, oct = idx & 7;
    const int k0 = oct * 8;
    const float* src = (m == 0 ? W3 : m == 1 ? W0 : m == 2 ? W1 : W2) + l * 4096;
    const size_t dst = (size_t)mat * 4096 +
                       ((size_t)((co >> 4) * 2 + (k0 >> 5)) << 9) +
                       (((co & 15) + 16 * ((k0 >> 3) & 3)) << 3);
    unsigned short w[8];
#pragma unroll
    for (int j = 0; j < 8; ++j) w[j] = f2bf(src[(k0 + j) * 64 + co]);
    *(uint4*)(Wall + dst) = *(const uint4*)w;
  }
}

// ---------------------------------------------------------------------------
// h0 kernel (32-row tiles, grid 256): h0 = relu(BN_init(hs @ Wi)).
// ---------------------------------------------------------------------------
__launch_bounds__(256, 1)
__global__ void h0_kernel(const float* __restrict__ hs,
                          const unsigned short* __restrict__ Wp,
                          const float* __restrict__ mean,
                          const float* __restrict__ var,
                          const float* __restrict__ gamma,
                          const float* __restrict__ beta,
                          unsigned short* __restrict__ operm,
                          unsigned short* __restrict__ olin) {
  const int b = blockIdx.y;
  const int R0 = blockIdx.x * 32;
  const int tid = threadIdx.x;
  const int w = tid >> 6, l = tid & 63;
  const int lr = l & 15, q = l >> 4;
  const int nsub = (w & 1) * 16;
  const int cstart = (w >> 1) * 2;

  const float* Af =
      hs + ((size_t)b << 18) + (size_t)(R0 + nsub + lr) * 512 + q * 8;
  const unsigned short* Xf = Wp + cstart * 8192 + l * 8;

  f32x4 acc[2] = {{0.f, 0.f, 0.f, 0.f}, {0.f, 0.f, 0.f, 0.f}};
  float4 ral[2][2];
  bf16x8 xb[2][2];
#define LD0(S_, T_)                                                       \
  {                                                                       \
    ral[S_][0] = *(const float4*)(Af + (T_)*32);                          \
    ral[S_][1] = *(const float4*)(Af + (T_)*32 + 4);                      \
    xb[S_][0] = *(const bf16x8*)(Xf + (T_)*512);                          \
    xb[S_][1] = *(const bf16x8*)(Xf + 8192 + (T_)*512);                   \
  }
  LD0(0, 0)
#pragma unroll
  for (int t = 0; t < 16; ++t) {
    const int cur = t & 1;
    if (t + 1 < 16) LD0(cur ^ 1, t + 1)
    union { bf16x8 v; unsigned int u[4]; } cv;
    cv.u[0] = pk2(ral[cur][0].x, ral[cur][0].y);
    cv.u[1] = pk2(ral[cur][0].z, ral[cur][0].w);
    cv.u[2] = pk2(ral[cur][1].x, ral[cur][1].y);
    cv.u[3] = pk2(ral[cur][1].z, ral[cur][1].w);
#pragma unroll
    for (int c = 0; c < 2; ++c)
      acc[c] = __builtin_amdgcn_mfma_f32_16x16x32_bf16(cv.v, xb[cur][c], acc[c], 0, 0, 0);
  }
#undef LD0

  __shared__ __align__(16) unsigned short Tfn[64][40];
  __shared__ __align__(16) unsigned short Tnf[32][72];
  float sc[4], mu[4], bt[4];
#pragma unroll
  for (int i = 0; i < 4; ++i) {
    int n = R0 + nsub + q * 4 + i;
    sc[i] = rsqrtf(var[n] + 1e-5f) * gamma[n];
    mu[i] = mean[n];
    bt[i] = beta[n];
  }
#pragma unroll
  for (int c = 0; c < 2; ++c) {
    const int f = (cstart + c) * 16 + lr;
    ushort4 wv;
#pragma unroll
    for (int i = 0; i < 4; ++i) {
      float v = fmaxf(fmaf(acc[c][i] - mu[i], sc[i], bt[i]), 0.f);
      unsigned short uv = f2bf(v);
      ((unsigned short*)&wv)[i] = uv;
      Tnf[nsub + q * 4 + i][f] = uv;
    }
    *(ushort4*)&Tfn[f][nsub + q * 4] = wv;
  }
  __syncthreads();
  {
    const int f = tid >> 2, oc = tid & 3;
    const int n = R0 + oc * 8;
    const size_t dst = ((size_t)b << 15) +
                       ((size_t)((f >> 4) * 16 + (n >> 5)) << 9) +
                       (((f & 15) + 16 * ((n >> 3) & 3)) << 3);
    *(uint4*)(operm + dst) = *(const uint4*)&Tfn[f][oc * 8];
    const int nl = tid >> 3, oc8 = tid & 7;
    *(uint4*)(olin + ((size_t)b << 15) + (size_t)(R0 + nl) * 64 + oc8 * 8) =
        *(const uint4*)&Tnf[nl][oc8 * 8];
  }
}

// ---------------------------------------------------------------------------
// layer0: r12 structure (fp32 staged, NSEG=1) + emits bf16 a0/a1/a2/asum.
// ---------------------------------------------------------------------------
struct L0Args {
  const float* Af0;
  const float* Af1;
  const float* Af2;
  const unsigned short* Xh;
  const unsigned short* hlin;
  const unsigned short* Wl;
  const float *bias, *mean, *var, *gamma, *beta;
  unsigned short* hperm_o;
  unsigned short* hlin_o;
  unsigned short* Po[3];
  unsigned short* ab0;
  unsigned short* ab1;
  unsigned short* ab2;
  unsigned short* absum;
};

__launch_bounds__(256, 2)
__global__ void layer0_kernel(L0Args La) {
  const int flat = blockIdx.x;  // 512
  const int b = (flat & 7) + 8 * ((flat >> 3) & 1);
  const int R0 = (flat >> 4) * 16;
  const int tid = threadIdx.x;
  const int w = tid >> 6, l = tid & 63;
  const int lr = l & 15, q = l >> 4;

  __shared__ __align__(16) float Asg[2][3][16][64];
  __shared__ __align__(16) unsigned short Tnf[3][16][72];
  __shared__ __align__(16) unsigned short Tfn[3][64][24];
  __shared__ __align__(16) unsigned short Hfn[64][24];
  __shared__ __align__(16) unsigned short Hnf[16][72];

  const float* Az = (w == 0) ? La.Af0 : (w == 1) ? La.Af1 : La.Af2;
  const float* Abase = Az + ((size_t)b << 18) + (size_t)R0 * 512;
  size_t aoff[4];
#pragma unroll
  for (int c = 0; c < 4; ++c) {
    const int arow = c * 4 + (l >> 4);
    const int agc = (l & 15) ^ arow;
    aoff[c] = (size_t)arow * 512 + agc * 4;
  }

  const size_t xoff = ((size_t)b << 15) + (size_t)w * 8192 + l * 8;
  const unsigned short* Xhp = La.Xh + xoff;

  f32x4 acc[3] = {{0.f, 0.f, 0.f, 0.f},
                  {0.f, 0.f, 0.f, 0.f},
                  {0.f, 0.f, 0.f, 0.f}};
  bf16x8 rxh[2][2];

#define STAGE0(BB, T)                                                    \
  if (w < 3) {                                                           \
    _Pragma("unroll") for (int c = 0; c < 4; ++c)                        \
        gload_lds16(Abase + aoff[c] + (T)*64, &Asg[BB][w][c * 4][0]);    \
  }
#define LOADX0(S_, T_)                                                   \
  {                                                                      \
    rxh[S_][0] = *(const bf16x8*)(Xhp + (2 * (T_)) * 512);               \
    rxh[S_][1] = *(const bf16x8*)(Xhp + (2 * (T_) + 1) * 512);           \
  }

  STAGE0(0, 0)
  LOADX0(0, 0)
  __syncthreads();

  const int er = tid >> 4, esc = tid & 15, egc = esc ^ er;

#pragma unroll
  for (int t = 0; t < 8; ++t) {
    const int cur = t & 1;
    if (t + 1 < 8) {
      STAGE0(cur ^ 1, t + 1)
      LOADX0(cur ^ 1, t + 1)
    }
#pragma unroll
    for (int kf = 0; kf < 2; ++kf) {
      float4 fa[3], fb[3];
#pragma unroll
      for (int z = 0; z < 3; ++z) {
        fa[z] = *(const float4*)&Asg[cur][z][lr][((kf * 8 + 2 * q) ^ lr) << 2];
        fb[z] = *(const float4*)&Asg[cur][z][lr][((kf * 8 + 2 * q + 1) ^ lr) << 2];
      }
#pragma unroll
      for (int z = 0; z < 3; ++z) {
        union { bf16x8 v; unsigned int u[4]; } cv;
        cv.u[0] = pk2(fa[z].x, fa[z].y);
        cv.u[1] = pk2(fa[z].z, fa[z].w);
        cv.u[2] = pk2(fb[z].x, fb[z].y);
        cv.u[3] = pk2(fb[z].z, fb[z].w);
        acc[z] = __builtin_amdgcn_mfma_f32_16x16x32_bf16(cv.v, rxh[cur][kf],
                                                         acc[z], 0, 0, 0);
      }
    }
    // EMIT bf16 adjacency (linear) from the staged fp32 tile
    {
      float4 v0 = *(const float4*)&Asg[cur][0][er][esc * 4];
      float4 v1 = *(const float4*)&Asg[cur][1][er][esc * 4];
      float4 v2 = *(const float4*)&Asg[cur][2][er][esc * 4];
      const size_t go =
          ((size_t)b << 18) + (size_t)(R0 + er) * 512 + t * 64 + egc * 4;
      uint2 wv;
      wv.x = pk2(v0.x, v0.y); wv.y = pk2(v0.z, v0.w);
      *(uint2*)(La.ab0 + go) = wv;
      wv.x = pk2(v1.x, v1.y); wv.y = pk2(v1.z, v1.w);
      *(uint2*)(La.ab1 + go) = wv;
      wv.x = pk2(v2.x, v2.y); wv.y = pk2(v2.z, v2.w);
      *(uint2*)(La.ab2 + go) = wv;
      wv.x = pk2(v0.x + v1.x + v2.x, v0.y + v1.y + v2.y);
      wv.y = pk2(v0.z + v1.z + v2.z, v0.w + v1.w + v2.w);
      *(uint2*)(La.absum + go) = wv;
    }
    __syncthreads();
  }
#undef STAGE0
#undef LOADX0

#pragma unroll
  for (int z = 0; z < 3; ++z) {
    const int f = w * 16 + lr;
    ushort4 wv;
#pragma unroll
    for (int i = 0; i < 4; ++i) {
      unsigned short uv = f2bf(acc[z][i]);
      ((unsigned short*)&wv)[i] = uv;
      Tnf[z][q * 4 + i][f] = uv;
    }
    *(ushort4*)&Tfn[z][f][q * 4] = wv;
  }
  __syncthreads();

  if (tid < 128) {
    const int f = tid >> 1, o = tid & 1;
    const int n = R0 + o * 8;
    const size_t dst = ((size_t)b << 15) +
                       ((size_t)((f >> 4) * 16 + (n >> 5)) << 9) +
                       (((f & 15) + 16 * ((n >> 3) & 3)) << 3);
#pragma unroll
    for (int z = 0; z < 3; ++z)
      *(uint4*)(La.Po[z] + dst) = *(const uint4*)&Tfn[z][f][o * 8];
  }

  f32x4 acch = {0.f, 0.f, 0.f, 0.f};
#pragma unroll
  for (int m = 0; m < 4; ++m) {
#pragma unroll
    for (int ks = 0; ks < 2; ++ks) {
      bf16x8 af;
      if (m == 0)
        af = *(const bf16x8*)(La.hlin + ((size_t)b << 15) +
                              (size_t)(R0 + lr) * 64 + q * 8 + ks * 32);
      else
        af = *(const bf16x8*)&Tnf[m - 1][lr][q * 8 + ks * 32];
      const bf16x8 bf_ = *(const bf16x8*)(La.Wl + m * 4096 +
                                          ((size_t)(w * 2 + ks) << 9) + l * 8);
      acch = __builtin_amdgcn_mfma_f32_16x16x32_bf16(af, bf_, acch, 0, 0, 0);
    }
  }

  {
    float sc[4], mu[4], bt[4];
#pragma unroll
    for (int i = 0; i < 4; ++i) {
      int n = R0 + q * 4 + i;
      sc[i] = rsqrtf(La.var[n] + 1e-5f) * La.gamma[n];
      mu[i] = La.mean[n];
      bt[i] = La.beta[n];
    }
    const int f = w * 16 + lr;
    const float bia = La.bias[f];
    ushort4 wv;
#pragma unroll
    for (int i = 0; i < 4; ++i) {
      float v = acch[i] + bia;
      v = fmaxf(fmaf(v - mu[i], sc[i], bt[i]), 0.f);
      unsigned short uv = f2bf(v);
      ((unsigned short*)&wv)[i] = uv;
      Hnf[q * 4 + i][f] = uv;
    }
    *(ushort4*)&Hfn[f][q * 4] = wv;
  }
  __syncthreads();

  if (tid < 128) {
    const int f = tid >> 1, o = tid & 1;
    const int n = R0 + o * 8;
    const size_t dst = ((size_t)b << 15) +
                       ((size_t)((f >> 4) * 16 + (n >> 5)) << 9) +
                       (((f & 15) + 16 * ((n >> 3) & 3)) << 3);
    *(uint4*)(La.hperm_o + dst) = *(const uint4*)&Hfn[f][o * 8];
    const int nl = tid >> 3, oc8 = tid & 7;
    *(uint4*)(La.hlin_o + ((size_t)b << 15) + (size_t)(R0 + nl) * 64 +
              oc8 * 8) = *(const uint4*)&Hnf[nl][oc8 * 8];
  }
}

// ---------------------------------------------------------------------------
// layerN (L1/L2): r12 pipeline shape, but stages bf16 {a0,a1,a2,asum}
// (wave w stages tile w) -> ds_read_b128 IS the MFMA fragment (no pack VALU).
// ---------------------------------------------------------------------------
struct LNArgs {
  const unsigned short* ab[4];  // a0,a1,a2,absum bf16 linear
  const unsigned short* Xh;
  const unsigned short* XP[3];
  const unsigned short* hlin;
  const unsigned short* Wl;
  const float *bias, *mean, *var, *gamma, *beta;
  unsigned short* hperm_o;
  unsigned short* hlin_o;
  unsigned short* Po[3];
};

__launch_bounds__(256, 2)
__global__ void layerN_kernel(LNArgs La) {
  const int flat = blockIdx.x;  // 512; flat&7 = XCD
  const int b = (flat & 7) + 8 * ((flat >> 3) & 1);
  const int R0 = (flat >> 4) * 16;
  const int tid = threadIdx.x;
  const int w = tid >> 6, l = tid & 63;
  const int lr = l & 15, q = l >> 4;

  __shared__ __align__(16) unsigned short Asg[2][4][16][64];  // 16 KB
  __shared__ __align__(16) unsigned short Tnf[3][16][72];
  __shared__ __align__(16) unsigned short Tfn[3][64][24];
  __shared__ __align__(16) unsigned short Hfn[64][24];
  __shared__ __align__(16) unsigned short Hnf[16][72];

  // staging: wave w stages tile w (a0/a1/a2/asum); 2 gload calls/lane.
  const unsigned short* Azb =
      La.ab[w] + ((size_t)b << 18) + (size_t)R0 * 512;
  size_t aoff[2];
#pragma unroll
  for (int c = 0; c < 2; ++c) {
    const int fl = c * 64 + l;
    const int srow = fl >> 3, schunk = fl & 7;
    const int gchunk = schunk ^ (srow & 7);
    aoff[c] = (size_t)srow * 512 + gchunk * 8;
  }

  const size_t xoff = ((size_t)b << 15) + (size_t)w * 8192 + l * 8;
  const unsigned short* Xhp = La.Xh + xoff;
  const unsigned short* XP0p = La.XP[0] + xoff;
  const unsigned short* XP1p = La.XP[1] + xoff;
  const unsigned short* XP2p = La.XP[2] + xoff;

  f32x4 acc[3] = {{0.f, 0.f, 0.f, 0.f},
                  {0.f, 0.f, 0.f, 0.f},
                  {0.f, 0.f, 0.f, 0.f}};
  bf16x8 rxh[2][2];
  bf16x8 rxp[2][3][2];

#define STAGEN(BB, T)                                                     \
  {                                                                       \
    _Pragma("unroll") for (int c = 0; c < 2; ++c)                         \
        gload_lds16b(Azb + aoff[c] + (T)*64, &Asg[BB][w][0][0] + c * 512); \
  }
#define LOADXN(S_, T_)                                                   \
  {                                                                      \
    rxh[S_][0] = *(const bf16x8*)(Xhp + (2 * (T_)) * 512);               \
    rxh[S_][1] = *(const bf16x8*)(Xhp + (2 * (T_) + 1) * 512);           \
    rxp[S_][0][0] = *(const bf16x8*)(XP0p + (2 * (T_)) * 512);           \
    rxp[S_][0][1] = *(const bf16x8*)(XP0p + (2 * (T_) + 1) * 512);       \
    rxp[S_][1][0] = *(const bf16x8*)(XP1p + (2 * (T_)) * 512);           \
    rxp[S_][1][1] = *(const bf16x8*)(XP1p + (2 * (T_) + 1) * 512);       \
    rxp[S_][2][0] = *(const bf16x8*)(XP2p + (2 * (T_)) * 512);           \
    rxp[S_][2][1] = *(const bf16x8*)(XP2p + (2 * (T_) + 1) * 512);       \
  }

  STAGEN(0, 0)
  LOADXN(0, 0)
  __syncthreads();

#pragma unroll
  for (int t = 0; t < 8; ++t) {
    const int cur = t & 1;
    if (t + 1 < 8) {
      STAGEN(cur ^ 1, t + 1)
      LOADXN(cur ^ 1, t + 1)
    }
#pragma unroll
    for (int kf = 0; kf < 2; ++kf) {
      const int ck = ((kf * 4 + q) ^ (lr & 7)) * 8;
      bf16x8 azf[3];
#pragma unroll
      for (int z = 0; z < 3; ++z) azf[z] = *(const bf16x8*)&Asg[cur][z][lr][ck];
      const bf16x8 asumf = *(const bf16x8*)&Asg[cur][3][lr][ck];
#pragma unroll
      for (int z = 0; z < 3; ++z) {
        acc[z] = __builtin_amdgcn_mfma_f32_16x16x32_bf16(azf[z], rxh[cur][kf],
                                                         acc[z], 0, 0, 0);
        acc[z] = __builtin_amdgcn_mfma_f32_16x16x32_bf16(
            asumf, rxp[cur][z][kf], acc[z], 0, 0, 0);
      }
    }
    __syncthreads();
  }
#undef STAGEN
#undef LOADXN

#pragma unroll
  for (int z = 0; z < 3; ++z) {
    const int f = w * 16 + lr;
    ushort4 wv;
#pragma unroll
    for (int i = 0; i < 4; ++i) {
      unsigned short uv = f2bf(acc[z][i]);
      ((unsigned short*)&wv)[i] = uv;
      Tnf[z][q * 4 + i][f] = uv;
    }
    *(ushort4*)&Tfn[z][f][q * 4] = wv;
  }
  __syncthreads();

  if (La.Po[0] != nullptr && tid < 128) {
    const int f = tid >> 1, o = tid & 1;
    const int n = R0 + o * 8;
    const size_t dst = ((size_t)b << 15) +
                       ((size_t)((f >> 4) * 16 + (n >> 5)) << 9) +
                       (((f & 15) + 16 * ((n >> 3) & 3)) << 3);
#pragma unroll
    for (int z = 0; z < 3; ++z)
      *(uint4*)(La.Po[z] + dst) = *(const uint4*)&Tfn[z][f][o * 8];
  }

  f32x4 acch = {0.f, 0.f, 0.f, 0.f};
#pragma unroll
  for (int m = 0; m < 4; ++m) {
#pragma unroll
    for (int ks = 0; ks < 2; ++ks) {
      bf16x8 af;
      if (m == 0)
        af = *(const bf16x8*)(La.hlin + ((size_t)b << 15) +
                              (size_t)(R0 + lr) * 64 + q * 8 + ks * 32);
      else
        af = *(const bf16x8*)&Tnf[m - 1][lr][q * 8 + ks * 32];
      const bf16x8 bf_ = *(const bf16x8*)(La.Wl + m * 4096 +
                                          ((size_t)(w * 2 + ks) << 9) + l * 8);
      acch = __builtin_amdgcn_mfma_f32_16x16x32_bf16(af, bf_, acch, 0, 0, 0);
    }
  }

  {
    float sc[4], mu[4], bt[4];
#pragma unroll
    for (int i = 0; i < 4; ++i) {
      int n = R0 + q * 4 + i;
      sc[i] = rsqrtf(La.var[n] + 1e-5f) * La.gamma[n];
      mu[i] = La.mean[n];
      bt[i] = La.beta[n];
    }
    const int f = w * 16 + lr;
    const float bia = La.bias[f];
    ushort4 wv;
#pragma unroll
    for (int i = 0; i < 4; ++i) {
      float v = acch[i] + bia;
      v = fmaxf(fmaf(v - mu[i], sc[i], bt[i]), 0.f);
      unsigned short uv = f2bf(v);
      ((unsigned short*)&wv)[i] = uv;
      Hnf[q * 4 + i][f] = uv;
    }
    *(ushort4*)&Hfn[f][q * 4] = wv;
  }
  __syncthreads();

  if (tid < 128) {
    const int f = tid >> 1, o = tid & 1;
    const int n = R0 + o * 8;
    const size_t dst = ((size_t)b << 15) +
                       ((size_t)((f >> 4) * 16 + (n >> 5)) << 9) +
                       (((f & 15) + 16 * ((n >> 3) & 3)) << 3);
    *(uint4*)(La.hperm_o + dst) = *(const uint4*)&Hfn[f][o * 8];
    if (La.hlin_o != nullptr) {
      const int nl = tid >> 3, oc8 = tid & 7;
      *(uint4*)(La.hlin_o + ((size_t)b << 15) + (size_t)(R0 + nl) * 64 +
                oc8 * 8) = *(const uint4*)&Hnf[nl][oc8 * 8];
    }
  }
}

// ---------------------------------------------------------------------------
// head: sum over n (B-perm h3) -> BN+ReLU -> FC(512) -> softmax. block per b.
// ---------------------------------------------------------------------------
__launch_bounds__(256)
__global__ void head_kernel(const unsigned short* __restrict__ h3p,
                            const float* __restrict__ gmean,
                            const float* __restrict__ gvar,
                            const float* __restrict__ ggamma,
                            const float* __restrict__ gbeta,
                            const float* __restrict__ fc_w,
                            const float* __restrict__ fc_b,
                            float* __restrict__ out) {
  const int b = blockIdx.x;
  const int t = threadIdx.x;
  __shared__ float part[256];
  __shared__ float gh[64];
  __shared__ float red[256];

  const int f = t >> 2, q = t & 3;
  const unsigned short* hp = h3p + ((size_t)b << 15);
  float s = 0.f;
#pragma unroll
  for (int m = 0; m < 16; ++m) {
    const int n = q * 128 + m * 8;
    const size_t off = ((size_t)((f >> 4) * 16 + (n >> 5)) << 9) +
                       (((f & 15) + 16 * ((n >> 3) & 3)) << 3);
    u16x8 v = *(const u16x8*)(hp + off);
#pragma unroll
    for (int e = 0; e < 8; ++e) s += bf2f((unsigned short)v[e]);
  }
  part[t] = s;
  __syncthreads();
  if (t < 64) {
    float sum = part[t * 4] + part[t * 4 + 1] + part[t * 4 + 2] + part[t * 4 + 3];
    float sc = rsqrtf(gvar[t] + 1e-5f) * ggamma[t];
    float v = fmaf(sum - gmean[t], sc, gbeta[t]);
    gh[t] = v > 0.f ? v : 0.f;
  }
  __syncthreads();

  float lg[2];
#pragma unroll
  for (int rep = 0; rep < 2; ++rep) {
    const int a = t + rep * 256;
    const float* __restrict__ wv = fc_w + (size_t)a * Fn;
    float acc = fc_b[a];
#pragma unroll 8
    for (int kk = 0; kk < 64; ++kk) acc = fmaf(gh[kk], wv[kk], acc);
    lg[rep] = acc;
  }
  red[t] = fmaxf(lg[0], lg[1]);
  __syncthreads();
  for (int off = 128; off > 0; off >>= 1) {
    if (t < off) red[t] = fmaxf(red[t], red[t + off]);
    __syncthreads();
  }
  const float mx = red[0];
  __syncthreads();
  const float e0 = __expf(lg[0] - mx), e1 = __expf(lg[1] - mx);
  red[t] = e0 + e1;
  __syncthreads();
  for (int off = 128; off > 0; off >>= 1) {
    if (t < off) red[t] += red[t + off];
    __syncthreads();
  }
  const float inv = 1.f / red[0];
  out[(size_t)b * Aout + t] = e0 * inv;
  out[(size_t)b * Aout + t + 256] = e1 * inv;
}

// ---------------------------------------------------------------------------
extern "C" void kernel_launch(void* const* d_in, const int* in_sizes, int n_in,
                              void* d_out, int out_size, void* d_ws,
                              size_t ws_size, hipStream_t stream) {
  (void)in_sizes; (void)n_in; (void)out_size; (void)ws_size;
  const float* hs_init = (const float*)d_in[0];
  const float* adjs0 = (const float*)d_in[1];
  const float* adjs1 = (const float*)d_in[2];
  const float* adjs2 = (const float*)d_in[3];
  const float* W_init = (const float*)d_in[4];
  const float* W0 = (const float*)d_in[5];
  const float* W1 = (const float*)d_in[6];
  const float* W2 = (const float*)d_in[7];
  const float* W3 = (const float*)d_in[8];
  const float* bvec = (const float*)d_in[9];
  const float* fc1_w = (const float*)d_in[10];
  const float* fc1_b = (const float*)d_in[11];
  const float* bn_init_mean = (const float*)d_in[12];
  const float* bn_init_var = (const float*)d_in[13];
  const float* bn_init_gamma = (const float*)d_in[14];
  const float* bn_init_beta = (const float*)d_in[15];
  const float* bn_layer_mean = (const float*)d_in[16];
  const float* bn_layer_var = (const float*)d_in[17];
  const float* bn_layer_gamma = (const float*)d_in[18];
  const float* bn_layer_beta = (const float*)d_in[19];
  const float* bn_graph_mean = (const float*)d_in[20];
  const float* bn_graph_var = (const float*)d_in[21];
  const float* bn_graph_gamma = (const float*)d_in[22];
  const float* bn_graph_beta = (const float*)d_in[23];

  const size_t NF = (size_t)Bn * Fn * Nn;   // 524,288
  const size_t ADJ = (size_t)Bn * Nn * Nn;  // 4,194,304

  unsigned short* wsu = (unsigned short*)d_ws;
  unsigned short* Wp = wsu;            // 32768
  unsigned short* Wall = Wp + 32768;   // 49152
  unsigned short* hApe = Wall + 49152;
  unsigned short* hBpe = hApe + NF;
  unsigned short* hAli = hBpe + NF;
  unsigned short* hBli = hAli + NF;
  unsigned short* PA0 = hBli + NF;
  unsigned short* PA1 = PA0 + NF;
  unsigned short* PA2 = PA1 + NF;
  unsigned short* PB0 = PA2 + NF;
  unsigned short* PB1 = PB0 + NF;
  unsigned short* PB2 = PB1 + NF;
  unsigned short* ab0 = PB2 + NF;
  unsigned short* ab1 = ab0 + ADJ;
  unsigned short* ab2 = ab1 + ADJ;
  unsigned short* absum = ab2 + ADJ;

  prep_kernel<<<dim3(40), dim3(256), 0, stream>>>(W_init, Wp, W0, W1, W2, W3,
                                                  Wall);

  h0_kernel<<<dim3(16, Bn), dim3(256), 0, stream>>>(
      hs_init, Wp, bn_init_mean, bn_init_var, bn_init_gamma, bn_init_beta,
      hApe, hAli);

  // L0 (fp32 staged; emits bf16 adjacency + sum)
  {
    L0Args La = {};
    La.Af0 = adjs0; La.Af1 = adjs1; La.Af2 = adjs2;
    La.Xh = hApe; La.hlin = hAli;
    La.Wl = Wall;
    La.bias = bvec; La.mean = bn_layer_mean; La.var = bn_layer_var;
    La.gamma = bn_layer_gamma; La.beta = bn_layer_beta;
    La.hperm_o = hBpe; La.hlin_o = hBli;
    La.Po[0] = PA0; La.Po[1] = PA1; La.Po[2] = PA2;
    La.ab0 = ab0; La.ab1 = ab1; La.ab2 = ab2; La.absum = absum;
    layer0_kernel<<<dim3(512), dim3(256), 0, stream>>>(La);
  }
  // L1 (bf16 staged, no pack VALU)
  {
    LNArgs La = {};
    La.ab[0] = ab0; La.ab[1] = ab1; La.ab[2] = ab2; La.ab[3] = absum;
    La.Xh = hBpe; La.hlin = hBli;
    La.XP[0] = PA0; La.XP[1] = PA1; La.XP[2] = PA2;
    La.Wl = Wall + 4 * 4096;
    La.bias = bvec + 64; La.mean = bn_layer_mean + 512;
    La.var = bn_layer_var + 512; La.gamma = bn_layer_gamma + 512;
    La.beta = bn_layer_beta + 512;
    La.hperm_o = hApe; La.hlin_o = hAli;
    La.Po[0] = PB0; La.Po[1] = PB1; La.Po[2] = PB2;
    layerN_kernel<<<dim3(512), dim3(256), 0, stream>>>(La);
  }
  // L2
  {
    LNArgs La = {};
    La.ab[0] = ab0; La.ab[1] = ab1; La.ab[2] = ab2; La.ab[3] = absum;
    La.Xh = hApe; La.hlin = hAli;
    La.XP[0] = PB0; La.XP[1] = PB1; La.XP[2] = PB2;
    La.Wl = Wall + 8 * 4096;
    La.bias = bvec + 128; La.mean = bn_layer_mean + 1024;
    La.var = bn_layer_var + 1024; La.gamma = bn_layer_gamma + 1024;
    La.beta = bn_layer_beta + 1024;
    La.hperm_o = hBpe; La.hlin_o = nullptr;
    La.Po[0] = nullptr; La.Po[1] = nullptr; La.Po[2] = nullptr;
    layerN_kernel<<<dim3(512), dim3(256), 0, stream>>>(La);
  }

  head_kernel<<<dim3(Bn), dim3(256), 0, stream>>>(
      hBpe, bn_graph_mean, bn_graph_var, bn_graph_gamma, bn_graph_beta, fc1_w,
      fc1_b, (float*)d_out);
}